// Round 1
// baseline (343.038 us; speedup 1.0000x reference)
//
#include <hip/hip_runtime.h>
#include <hip/hip_bf16.h>

#define HID 2048
#define INTER 8192
#define QKV 8192
#define TV 4096
#define NVH 32
#define KD 128
#define VD 128
#define NKH 16
#define CK 4
#define NPROJ (QKV + TV + 2*NVH)   // 12352

__device__ __forceinline__ float wave_sum(float v){
#pragma unroll
  for (int off = 32; off > 0; off >>= 1) v += __shfl_down(v, off, 64);
  return v;
}

// ---------------- RMSNorm with (1+w) scale: out = x * rsqrt(mean(x^2)+eps) * (1+w)
__global__ void rmsnorm_kernel(const float* __restrict__ x, const float* __restrict__ w,
                               float* __restrict__ out){
  int t = threadIdx.x; // 256 threads, HID=2048 -> 8 per thread
  float xs[8];
  float s = 0.f;
#pragma unroll
  for (int i = 0; i < 8; i++){ float v = x[t + i*256]; xs[i] = v; s += v*v; }
  __shared__ float red[4];
  float ps = wave_sum(s);
  if ((t & 63) == 0) red[t >> 6] = ps;
  __syncthreads();
  float tot = red[0] + red[1] + red[2] + red[3];
  float inv = rsqrtf(tot / (float)HID + 1e-6f);
#pragma unroll
  for (int i = 0; i < 8; i++){
    int idx = t + i*256;
    out[idx] = xs[i] * inv * (1.f + w[idx]);
  }
}

// ---------------- in_proj GEMV (12352 rows x 2048) + conv-state update fused in epilogue
__global__ void in_proj_kernel(const float* __restrict__ W, const float* __restrict__ h,
                               const float* __restrict__ conv_state, const float* __restrict__ conv_w,
                               float* __restrict__ conv_out, float* __restrict__ z,
                               float* __restrict__ ab, float* __restrict__ new_conv_state){
  int row  = blockIdx.x * 4 + (threadIdx.x >> 6);
  int lane = threadIdx.x & 63;
  const float4* W4 = (const float4*)W + (size_t)row * (HID/4);
  const float4* h4 = (const float4*)h;
  float acc = 0.f;
#pragma unroll
  for (int c = 0; c < HID/4/64; c++){           // 8 iters
    float4 a = W4[c*64 + lane];
    float4 b = h4[c*64 + lane];
    acc += a.x*b.x + a.y*b.y + a.z*b.z + a.w*b.w;
  }
  acc = wave_sum(acc);
  if (lane == 0){
    if (row < QKV){
      float c1 = conv_state[row*4+1], c2 = conv_state[row*4+2], c3 = conv_state[row*4+3];
      const float4 cw = ((const float4*)conv_w)[row];
      float s = c1*cw.x + c2*cw.y + c3*cw.z + acc*cw.w;
      conv_out[row] = s / (1.f + expf(-s));     // silu
      ((float4*)new_conv_state)[row] = make_float4(c1, c2, c3, acc);
    } else if (row < QKV + TV){
      z[row - QKV] = acc;
    } else {
      ab[row - (QKV + TV)] = acc;               // [0,32)=a_raw  [32,64)=b_raw
    }
  }
}

// ---------------- SSM delta-rule update, one block per head (256 thr: v = t&127, khalf = t>>7)
__global__ void ssm_kernel(const float* __restrict__ S, const float* __restrict__ conv_out,
                           const float* __restrict__ z, const float* __restrict__ ab,
                           const float* __restrict__ A_log, const float* __restrict__ dt_bias,
                           const float* __restrict__ norm_w,
                           float* __restrict__ newS, float* __restrict__ y_gated){
  int hh = blockIdx.x;
  int t  = threadIdx.x;       // 0..255
  int v  = t & 127;
  int half = t >> 7;
  __shared__ float s_q[KD], s_k[KD], sP[256], redq[4], redk[4], redy[4];

  float qr = 0.f, kr = 0.f;
  if (t < KD){
    int kvh = hh >> 1;                       // jnp.repeat(ratio=2)
    qr = conv_out[kvh*KD + t];
    kr = conv_out[NKH*KD + kvh*KD + t];
  }
  float q2 = wave_sum(qr*qr);
  float k2 = wave_sum(kr*kr);
  if ((t & 63) == 0){ redq[t>>6] = q2; redk[t>>6] = k2; }
  __syncthreads();
  float qs = redq[0]+redq[1]+redq[2]+redq[3];
  float ks = redk[0]+redk[1]+redk[2]+redk[3];
  if (t < KD){
    s_q[t] = qr / fmaxf(sqrtf(qs), 1e-12f);  // l2norm
    s_k[t] = kr / fmaxf(sqrtf(ks), 1e-12f);
  }
  __syncthreads();

  float a     = ab[hh] + dt_bias[hh];
  float sp    = log1pf(expf(a));             // softplus
  float decay = expf(-expf(A_log[hh]) * sp);
  float beta  = 1.f / (1.f + expf(-ab[NVH + hh]));

  const float* Sh  = S    + (size_t)hh * KD * VD;
  float*       nSh = newS + (size_t)hh * KD * VD;
  int k0 = half * 64;

  // pass 1: Sk[v] = sum_k S[k][v] * k[k]   (split k-range by half)
  float acc = 0.f;
#pragma unroll 8
  for (int kk = 0; kk < 64; kk++)
    acc += Sh[(k0+kk)*VD + v] * s_k[k0+kk];
  sP[t] = acc;
  __syncthreads();
  float Sk    = sP[v] + sP[128 + v];
  float vv    = conv_out[2*NKH*KD + hh*VD + v];
  float delta = vv - Sk;
  __syncthreads();                            // before reusing sP

  // pass 2: newS = decay*S + beta*k(x)delta ; y[v] = sum_k newS[k][v]*q[k]
  float y = 0.f;
#pragma unroll 8
  for (int kk = 0; kk < 64; kk++){
    int krow = k0 + kk;
    float ns = decay * Sh[krow*VD + v] + beta * s_k[krow] * delta;
    nSh[krow*VD + v] = ns;
    y += ns * s_q[krow];
  }
  sP[t] = y;
  __syncthreads();
  float yv = 0.f;
  if (t < VD) yv = sP[t] + sP[128 + t];
  float y2 = wave_sum(yv*yv);
  if ((t & 63) == 0) redy[t>>6] = y2;
  __syncthreads();
  float var = (redy[0]+redy[1]+redy[2]+redy[3]) / (float)VD;
  if (t < VD){
    float yn = yv * rsqrtf(var + 1e-6f) * norm_w[t];   // note: norm_w, no 1+
    float zz = z[hh*VD + t];
    y_gated[hh*VD + t] = yn * (zz / (1.f + expf(-zz))); // * silu(z)
  }
}

// ---------------- out_proj GEMV (2048 rows x 4096) + residual -> x1
__global__ void out_proj_kernel(const float* __restrict__ W, const float* __restrict__ yg,
                                const float* __restrict__ x, float* __restrict__ x1){
  int row  = blockIdx.x * 4 + (threadIdx.x >> 6);
  int lane = threadIdx.x & 63;
  const float4* W4 = (const float4*)W + (size_t)row * (TV/4);
  const float4* g4 = (const float4*)yg;
  float acc = 0.f;
#pragma unroll
  for (int c = 0; c < TV/4/64; c++){           // 16 iters
    float4 a = W4[c*64 + lane];
    float4 b = g4[c*64 + lane];
    acc += a.x*b.x + a.y*b.y + a.z*b.z + a.w*b.w;
  }
  acc = wave_sum(acc);
  if (lane == 0) x1[row] = x[row] + acc;
}

// ---------------- gate & up GEMV (8192 rows x 2048 each) + silu(g)*u
__global__ void gateup_kernel(const float* __restrict__ Wg, const float* __restrict__ Wu,
                              const float* __restrict__ hn, float* __restrict__ inter){
  int row  = blockIdx.x * 4 + (threadIdx.x >> 6);
  int lane = threadIdx.x & 63;
  const float4* G4 = (const float4*)Wg + (size_t)row * (HID/4);
  const float4* U4 = (const float4*)Wu + (size_t)row * (HID/4);
  const float4* h4 = (const float4*)hn;
  float g = 0.f, u = 0.f;
#pragma unroll
  for (int c = 0; c < HID/4/64; c++){          // 8 iters
    float4 b = h4[c*64 + lane];
    float4 a = G4[c*64 + lane];
    g += a.x*b.x + a.y*b.y + a.z*b.z + a.w*b.w;
    float4 e = U4[c*64 + lane];
    u += e.x*b.x + e.y*b.y + e.z*b.z + e.w*b.w;
  }
  g = wave_sum(g);
  u = wave_sum(u);
  if (lane == 0) inter[row] = (g / (1.f + expf(-g))) * u;
}

// ---------------- down GEMV (2048 rows x 8192) + residual -> x_out
__global__ void down_kernel(const float* __restrict__ W, const float* __restrict__ inter,
                            const float* __restrict__ x1, float* __restrict__ out){
  int row  = blockIdx.x * 4 + (threadIdx.x >> 6);
  int lane = threadIdx.x & 63;
  const float4* W4 = (const float4*)W + (size_t)row * (INTER/4);
  const float4* i4 = (const float4*)inter;
  float acc = 0.f;
#pragma unroll
  for (int c = 0; c < INTER/4/64; c++){        // 32 iters
    float4 a = W4[c*64 + lane];
    float4 b = i4[c*64 + lane];
    acc += a.x*b.x + a.y*b.y + a.z*b.z + a.w*b.w;
  }
  acc = wave_sum(acc);
  if (lane == 0) out[row] = x1[row] + acc;
}

extern "C" void kernel_launch(void* const* d_in, const int* in_sizes, int n_in,
                              void* d_out, int out_size, void* d_ws, size_t ws_size,
                              hipStream_t stream) {
  const float* x         = (const float*)d_in[0];
  const float* conv_st   = (const float*)d_in[1];
  const float* ssm_st    = (const float*)d_in[2];
  const float* in_ln_w   = (const float*)d_in[3];
  const float* in_proj_w = (const float*)d_in[4];
  const float* conv_w    = (const float*)d_in[5];
  const float* A_log     = (const float*)d_in[6];
  const float* dt_bias   = (const float*)d_in[7];
  const float* norm_w    = (const float*)d_in[8];
  const float* out_proj_w= (const float*)d_in[9];
  const float* post_ln_w = (const float*)d_in[10];
  const float* gate_w    = (const float*)d_in[11];
  const float* up_w      = (const float*)d_in[12];
  const float* down_w    = (const float*)d_in[13];

  float* out_x   = (float*)d_out;          // 2048
  float* out_cs  = out_x + HID;            // 8192*4
  float* out_ssm = out_cs + QKV*CK;        // 32*128*128

  float* ws       = (float*)d_ws;
  float* h        = ws;                    // 2048
  float* conv_out = h + HID;               // 8192
  float* z        = conv_out + QKV;        // 4096
  float* ab       = z + TV;                // 64
  float* y_gated  = ab + 64;               // 4096
  float* x1       = y_gated + TV;          // 2048
  float* hn       = x1 + HID;              // 2048
  float* inter    = hn + HID;              // 8192

  rmsnorm_kernel <<<1,         256, 0, stream>>>(x, in_ln_w, h);
  in_proj_kernel <<<NPROJ/4,   256, 0, stream>>>(in_proj_w, h, conv_st, conv_w,
                                                 conv_out, z, ab, out_cs);
  ssm_kernel     <<<NVH,       256, 0, stream>>>(ssm_st, conv_out, z, ab, A_log, dt_bias,
                                                 norm_w, out_ssm, y_gated);
  out_proj_kernel<<<HID/4,     256, 0, stream>>>(out_proj_w, y_gated, x, x1);
  rmsnorm_kernel <<<1,         256, 0, stream>>>(x1, post_ln_w, hn);
  gateup_kernel  <<<INTER/4,   256, 0, stream>>>(gate_w, up_w, hn, inter);
  down_kernel    <<<HID/4,     256, 0, stream>>>(down_w, inter, x1, out_x);
}

// Round 2
// 331.283 us; speedup vs baseline: 1.0355x; 1.0355x over previous
//
#include <hip/hip_runtime.h>
#include <hip/hip_bf16.h>

#define HID 2048
#define INTER 8192
#define QKV 8192
#define TV 4096
#define NVH 32
#define KD 128
#define VD 128
#define NKH 16
#define CK 4
#define NPROJ (QKV + TV + 2*NVH)   // 12352

__device__ __forceinline__ float wave_sum(float v){
#pragma unroll
  for (int off = 32; off > 0; off >>= 1) v += __shfl_down(v, off, 64);
  return v;
}

// Block-wide rmsnorm of a 2048-vector into LDS: s_h[i] = src[i]*rsqrt(mean+eps)*(1+w[i])
// Every block computes this redundantly (src/w are L2-hot: 16KB/block).
__device__ __forceinline__ void rmsnorm_to_lds(const float* __restrict__ src,
                                               const float* __restrict__ w,
                                               float* s_h, float* red){
  int t = threadIdx.x;
  float xs[8]; float s = 0.f;
#pragma unroll
  for (int i = 0; i < 8; i++){ float v = src[t + i*256]; xs[i] = v; s += v*v; }
  float ps = wave_sum(s);
  if ((t & 63) == 0) red[t >> 6] = ps;
  __syncthreads();
  float inv = rsqrtf((red[0]+red[1]+red[2]+red[3]) / (float)HID + 1e-6f);
#pragma unroll
  for (int i = 0; i < 8; i++){
    int idx = t + i*256;
    s_h[idx] = xs[i] * inv * (1.f + w[idx]);
  }
  __syncthreads();
}

// ---------------- fused: rmsnorm(x) -> in_proj GEMV (12352x2048) -> conv update
__global__ __launch_bounds__(256) void in_proj_fused(
    const float* __restrict__ x, const float* __restrict__ ln_w,
    const float* __restrict__ W, const float* __restrict__ conv_state,
    const float* __restrict__ conv_w, float* __restrict__ conv_out,
    float* __restrict__ z, float* __restrict__ ab, float* __restrict__ new_conv_state){
  __shared__ __align__(16) float s_h[HID];
  __shared__ float red[4];
  rmsnorm_to_lds(x, ln_w, s_h, red);

  int row  = blockIdx.x * 4 + (threadIdx.x >> 6);
  int lane = threadIdx.x & 63;
  const float4* W4 = (const float4*)W + (size_t)row * (HID/4);
  const float4* h4 = (const float4*)s_h;
  float acc = 0.f;
#pragma unroll
  for (int c = 0; c < HID/4/64; c++){            // 8 iters
    float4 a = W4[c*64 + lane];
    float4 b = h4[c*64 + lane];
    acc += a.x*b.x + a.y*b.y + a.z*b.z + a.w*b.w;
  }
  acc = wave_sum(acc);
  if (lane == 0){
    if (row < QKV){
      float c1 = conv_state[row*4+1], c2 = conv_state[row*4+2], c3 = conv_state[row*4+3];
      const float4 cw = ((const float4*)conv_w)[row];
      float s = c1*cw.x + c2*cw.y + c3*cw.z + acc*cw.w;
      conv_out[row] = s / (1.f + expf(-s));      // silu
      ((float4*)new_conv_state)[row] = make_float4(c1, c2, c3, acc);
    } else if (row < QKV + TV){
      z[row - QKV] = acc;
    } else {
      ab[row - (QKV + TV)] = acc;                // [0,32)=a_raw  [32,64)=b_raw
    }
  }
}

// ---------------- SSM delta-rule, one block/head; S half-column cached in regs
__global__ __launch_bounds__(256) void ssm_kernel(
    const float* __restrict__ S, const float* __restrict__ conv_out,
    const float* __restrict__ z, const float* __restrict__ ab,
    const float* __restrict__ A_log, const float* __restrict__ dt_bias,
    const float* __restrict__ norm_w,
    float* __restrict__ newS, float* __restrict__ y_gated){
  int hh = blockIdx.x;
  int t  = threadIdx.x;       // 0..255
  int v  = t & 127;
  int half = t >> 7;
  __shared__ float s_q[KD], s_k[KD], sP[256], redq[4], redk[4], redy[4];

  float qr = 0.f, kr = 0.f;
  if (t < KD){
    int kvh = hh >> 1;                       // repeat(ratio=2)
    qr = conv_out[kvh*KD + t];
    kr = conv_out[NKH*KD + kvh*KD + t];
  }
  float q2 = wave_sum(qr*qr);
  float k2 = wave_sum(kr*kr);
  if ((t & 63) == 0){ redq[t>>6] = q2; redk[t>>6] = k2; }
  __syncthreads();
  float qs = redq[0]+redq[1]+redq[2]+redq[3];
  float ks = redk[0]+redk[1]+redk[2]+redk[3];
  if (t < KD){
    s_q[t] = qr / fmaxf(sqrtf(qs), 1e-12f);  // l2norm
    s_k[t] = kr / fmaxf(sqrtf(ks), 1e-12f);
  }
  __syncthreads();

  float a     = ab[hh] + dt_bias[hh];
  float sp    = log1pf(expf(a));             // softplus
  float decay = expf(-expf(A_log[hh]) * sp);
  float beta  = 1.f / (1.f + expf(-ab[NVH + hh]));

  const float* Sh  = S    + (size_t)hh * KD * VD;
  float*       nSh = newS + (size_t)hh * KD * VD;
  int k0 = half * 64;

  // pass 1: Sk[v] = sum_k S[k][v]*k[k]; keep S column-half in registers
  float sreg[64];
  float acc = 0.f;
#pragma unroll
  for (int kk = 0; kk < 64; kk++){
    sreg[kk] = Sh[(k0+kk)*VD + v];
    acc += sreg[kk] * s_k[k0+kk];
  }
  sP[t] = acc;
  __syncthreads();
  float Sk    = sP[v] + sP[128 + v];
  float vv    = conv_out[2*NKH*KD + hh*VD + v];
  float delta = vv - Sk;
  __syncthreads();                            // before reusing sP

  // pass 2: newS = decay*S + beta*k(x)delta ; y[v] = sum_k newS[k][v]*q[k]
  float y = 0.f;
#pragma unroll
  for (int kk = 0; kk < 64; kk++){
    int krow = k0 + kk;
    float ns = decay * sreg[kk] + beta * s_k[krow] * delta;
    nSh[krow*VD + v] = ns;
    y += ns * s_q[krow];
  }
  sP[t] = y;
  __syncthreads();
  float yv = 0.f;
  if (t < VD) yv = sP[t] + sP[128 + t];
  float y2 = wave_sum(yv*yv);
  if ((t & 63) == 0) redy[t>>6] = y2;
  __syncthreads();
  float var = (redy[0]+redy[1]+redy[2]+redy[3]) / (float)VD;
  if (t < VD){
    float yn = yv * rsqrtf(var + 1e-6f) * norm_w[t];    // norm_w, no 1+
    float zz = z[hh*VD + t];
    y_gated[hh*VD + t] = yn * (zz / (1.f + expf(-zz))); // * silu(z)
  }
}

// ---------------- out_proj GEMV (2048 x 4096) + residual -> x1
__global__ __launch_bounds__(256) void out_proj_kernel(
    const float* __restrict__ W, const float* __restrict__ yg,
    const float* __restrict__ x, float* __restrict__ x1){
  int row  = blockIdx.x * 4 + (threadIdx.x >> 6);
  int lane = threadIdx.x & 63;
  const float4* W4 = (const float4*)W + (size_t)row * (TV/4);
  const float4* g4 = (const float4*)yg;
  float acc = 0.f;
#pragma unroll 8
  for (int c = 0; c < TV/4/64; c++){             // 16 iters
    float4 a = W4[c*64 + lane];
    float4 b = g4[c*64 + lane];
    acc += a.x*b.x + a.y*b.y + a.z*b.z + a.w*b.w;
  }
  acc = wave_sum(acc);
  if (lane == 0) x1[row] = x[row] + acc;
}

// ---------------- fused: rmsnorm(x1) -> gate&up GEMV (8192x2048 ea) -> silu(g)*u
__global__ __launch_bounds__(256) void gateup_fused(
    const float* __restrict__ x1, const float* __restrict__ ln_w,
    const float* __restrict__ Wg, const float* __restrict__ Wu,
    float* __restrict__ inter){
  __shared__ __align__(16) float s_h[HID];
  __shared__ float red[4];
  rmsnorm_to_lds(x1, ln_w, s_h, red);

  int row  = blockIdx.x * 4 + (threadIdx.x >> 6);
  int lane = threadIdx.x & 63;
  const float4* G4 = (const float4*)Wg + (size_t)row * (HID/4);
  const float4* U4 = (const float4*)Wu + (size_t)row * (HID/4);
  const float4* h4 = (const float4*)s_h;
  float g = 0.f, u = 0.f;
#pragma unroll 4
  for (int c = 0; c < HID/4/64; c++){            // 8 iters
    float4 b = h4[c*64 + lane];
    float4 a = G4[c*64 + lane];
    g += a.x*b.x + a.y*b.y + a.z*b.z + a.w*b.w;
    float4 e = U4[c*64 + lane];
    u += e.x*b.x + e.y*b.y + e.z*b.z + e.w*b.w;
  }
  g = wave_sum(g);
  u = wave_sum(u);
  if (lane == 0) inter[row] = (g / (1.f + expf(-g))) * u;
}

// ---------------- down GEMV (2048 x 8192) + residual -> x_out
__global__ __launch_bounds__(256) void down_kernel(
    const float* __restrict__ W, const float* __restrict__ inter,
    const float* __restrict__ x1, float* __restrict__ out){
  int row  = blockIdx.x * 4 + (threadIdx.x >> 6);
  int lane = threadIdx.x & 63;
  const float4* W4 = (const float4*)W + (size_t)row * (INTER/4);
  const float4* i4 = (const float4*)inter;
  float acc = 0.f;
#pragma unroll 8
  for (int c = 0; c < INTER/4/64; c++){          // 32 iters
    float4 a = W4[c*64 + lane];
    float4 b = i4[c*64 + lane];
    acc += a.x*b.x + a.y*b.y + a.z*b.z + a.w*b.w;
  }
  acc = wave_sum(acc);
  if (lane == 0) out[row] = x1[row] + acc;
}

extern "C" void kernel_launch(void* const* d_in, const int* in_sizes, int n_in,
                              void* d_out, int out_size, void* d_ws, size_t ws_size,
                              hipStream_t stream) {
  const float* x         = (const float*)d_in[0];
  const float* conv_st   = (const float*)d_in[1];
  const float* ssm_st    = (const float*)d_in[2];
  const float* in_ln_w   = (const float*)d_in[3];
  const float* in_proj_w = (const float*)d_in[4];
  const float* conv_w    = (const float*)d_in[5];
  const float* A_log     = (const float*)d_in[6];
  const float* dt_bias   = (const float*)d_in[7];
  const float* norm_w    = (const float*)d_in[8];
  const float* out_proj_w= (const float*)d_in[9];
  const float* post_ln_w = (const float*)d_in[10];
  const float* gate_w    = (const float*)d_in[11];
  const float* up_w      = (const float*)d_in[12];
  const float* down_w    = (const float*)d_in[13];

  float* out_x   = (float*)d_out;          // 2048
  float* out_cs  = out_x + HID;            // 8192*4
  float* out_ssm = out_cs + QKV*CK;        // 32*128*128

  float* ws       = (float*)d_ws;
  float* conv_out = ws;                    // 8192
  float* z        = conv_out + QKV;        // 4096
  float* ab       = z + TV;                // 64
  float* y_gated  = ab + 64;               // 4096
  float* x1       = y_gated + TV;          // 2048
  float* inter    = x1 + HID;              // 8192

  in_proj_fused  <<<NPROJ/4,  256, 0, stream>>>(x, in_ln_w, in_proj_w, conv_st, conv_w,
                                                conv_out, z, ab, out_cs);
  ssm_kernel     <<<NVH,      256, 0, stream>>>(ssm_st, conv_out, z, ab, A_log, dt_bias,
                                                norm_w, out_ssm, y_gated);
  out_proj_kernel<<<HID/4,    256, 0, stream>>>(out_proj_w, y_gated, x, x1);
  gateup_fused   <<<INTER/4,  256, 0, stream>>>(x1, post_ln_w, gate_w, up_w, inter);
  down_kernel    <<<HID/4,    256, 0, stream>>>(down_w, inter, x1, out_x);
}